// Round 4
// baseline (182.692 us; speedup 1.0000x reference)
//
#include <hip/hip_runtime.h>
#include <math.h>

// Problem constants (b=8, c=2048, e=64, h=8)
#define NTOK 16384
#define EDIM 64
#define HHE  512   // h*e
#define TPB  8     // tokens per block (R20: halved for 6 blocks/CU occupancy)
#define TOKPAD 260 // half2 slots per token row: 256 + 4 pad (16B-aligned rows)

typedef _Float16 half8 __attribute__((ext_vector_type(8)));   // MFMA operand type
typedef __fp16   half2v __attribute__((ext_vector_type(2)));  // builtin V2h type
typedef float    floatx4 __attribute__((ext_vector_type(4)));

__device__ __forceinline__ half8 cvt8(const float4 a, const float4 b) {
    half8 h;
    h[0] = (_Float16)a.x; h[1] = (_Float16)a.y;
    h[2] = (_Float16)a.z; h[3] = (_Float16)a.w;
    h[4] = (_Float16)b.x; h[5] = (_Float16)b.y;
    h[6] = (_Float16)b.z; h[7] = (_Float16)b.w;
    return h;
}

// fp32 += half2 . half2 (v_dot2_f32_f16); float fallback if builtin missing
__device__ __forceinline__ float dot2(half2v a, half2v b, float c) {
#if __has_builtin(__builtin_amdgcn_fdot2)
    return __builtin_amdgcn_fdot2(a, b, c, false);
#else
    return fmaf((float)a[0], (float)b[0], fmaf((float)a[1], (float)b[1], c));
#endif
}
__device__ __forceinline__ half2v pk(float x, float y) {
    return __builtin_amdgcn_cvt_pkrtz(x, y);   // v_cvt_pkrtz_f16_f32 (V2h)
}
union h2u { half2v h; unsigned int u; };

__device__ __forceinline__ float pgen(float z, float inv) {
    return z > 0.0f ? exp2f(inv * log2f(fmaxf(z, 1e-30f))) : 0.0f;
}

// ---------------------------------------------------------------------------
// Kernel 0: fp32 -> fp16 (RTN cast) for the 4 weight matrices only.
// Wq is pre-scaled by (alpha-1)/sqrt(e) = am1*0.125 so the score scale
// vanishes from the consumer hot loop. x is converted inline in kernel 1.
// All 4 matrices are 32768 elems -> grid (16,4), no bounds check needed.
// ---------------------------------------------------------------------------
__global__ __launch_bounds__(256) void cvt_fp16_kernel(
    const float* __restrict__ Wk, const float* __restrict__ Wq,
    const float* __restrict__ Wv, const float* __restrict__ Wu,
    __fp16* __restrict__ wkh, __fp16* __restrict__ wqh,
    __fp16* __restrict__ wvh, __fp16* __restrict__ wuh,
    const float* alpha_p)
{
    const int z = blockIdx.y;
    const float* src; __fp16* dst;
    float s = 1.0f;
    if      (z == 0) { src = Wk; dst = wkh; }
    else if (z == 1) { src = Wq; dst = wqh; s = (alpha_p[0] - 1.0f) * 0.125f; }
    else if (z == 2) { src = Wv; dst = wvh; }
    else             { src = Wu; dst = wuh; }
    const int idx = (blockIdx.x * 256 + threadIdx.x) * 8;
    float4 a = *(const float4*)(src + idx);
    float4 b = *(const float4*)(src + idx + 4);
    a.x *= s; a.y *= s; a.z *= s; a.w *= s;
    b.x *= s; b.y *= s; b.z *= s; b.w *= s;
    *(half8*)(dst + idx) = cvt8(a, b);
}

// ---------------------------------------------------------------------------
// Kernel 1: FULLY FUSED qkv + entmax-attention + output projection.
// R20: 8 tokens per block, 4 waves. LDS 49920 -> 24960 B => 6 blocks/CU
// resident (was 3), attacking the 40% VALU issue-idle at 26.7% occupancy.
// MFMA tiles keep 16 token columns with only 8 valid (m<8 gated stores);
// MFMA util is ~2% so the waste is free. Entmax math is the R18 scalar
// path (packed-fp32 reverted: VOP3P fp32 is half-issue-rate on CDNA4,
// regressed 96->119us). Wq pre-scale fold + inline x cast kept from R19.
// ---------------------------------------------------------------------------
__global__ __launch_bounds__(256) void qkv_attn_out_kernel(
    const float* __restrict__ x,
    const __fp16* __restrict__ wkh, const float* __restrict__ bk,
    const __fp16* __restrict__ wqh, const float* __restrict__ bq,
    const __fp16* __restrict__ wvh, const float* __restrict__ bv,
    const __fp16* __restrict__ wuh, const float* __restrict__ bu,
    float* __restrict__ out, const float* alpha_p)
{
    __shared__ __align__(16) half2v qT[TPB * TOKPAD];  // [tok][i*4+hpair] -> res overlay
    __shared__ __align__(16) half2v kT[TPB * TOKPAD];  // [tok][j*4 + hpair]
    __shared__ __align__(16) half2v vT[TPB * TOKPAD];  // [tok][h*32 + jpair]

    const int tid  = threadIdx.x;
    const int lane = tid & 63;
    const int w    = tid >> 6;
    const int tok0 = blockIdx.x * TPB;

    const int m    = lane & 15;            // MFMA token column (0..15; <8 valid)
    const int quad = lane >> 4;

    const float alpha = alpha_p[0];
    const float am1   = alpha - 1.0f;
    const float s_q   = am1 * 0.125f;      // matches cvt kernel's Wq scale

    // ---- x B-fragments: fp32 load + RTN cast (identical to old cvt path).
    // Lanes m>=8 load a clamped row; their MFMA columns are discarded.
    const int trow = tok0 + m < NTOK - 1 ? tok0 + m : NTOK - 1;
    const float* xrow = x + (size_t)trow * EDIM + quad * 8;
    half8 bfr[2];
    {
        const float4 a0 = *(const float4*)(xrow);
        const float4 a1 = *(const float4*)(xrow + 4);
        const float4 a2 = *(const float4*)(xrow + 32);
        const float4 a3 = *(const float4*)(xrow + 36);
        bfr[0] = cvt8(a0, a1);
        bfr[1] = cvt8(a2, a3);
    }

    // ---- producer: units w*3 .. w*3+2; unit = z*4 + ntile
    #pragma unroll
    for (int uu = 0; uu < 3; ++uu) {
        const int unit = w * 3 + uu;
        const int z    = unit >> 2;            // 0=k, 1=q, 2=v
        const int col0 = (unit & 3) * 128;
        const __fp16* W   = (z == 0) ? wkh : (z == 1) ? wqh : wvh;
        const float* bias = (z == 0) ? bk : (z == 1) ? bq : bv;
        half2v* dstT      = (z == 0) ? kT : (z == 1) ? qT : vT;
        // q path: W pre-scaled; bias scaled here via exact fmaf (bs=1 for k)
        const float bs    = (z == 1) ? s_q : 1.0f;

        #pragma unroll
        for (int ct = 0; ct < 8; ++ct) {
            const int n = col0 + ct * 16 + m;
            // permuted W row for q/k; natural for v
            const int grow = (z < 2) ? ((n & 7) * 64 + (n >> 3)) : n;
            const __fp16* wrow = W + (size_t)grow * EDIM + quad * 8;
            floatx4 acc = (floatx4){0.f, 0.f, 0.f, 0.f};
            #pragma unroll
            for (int kc = 0; kc < 2; ++kc) {
                const half8 af = *(const half8*)(wrow + kc * 32);  // direct fp16
                acc = __builtin_amdgcn_mfma_f32_16x16x32_f16(af, bfr[kc], acc, 0, 0, 0);
            }
            // lane's 4 regs = D rows quad*4+0..3, D col = m (token)
            h2u p0, p1;
            if (z < 2) {
                // output rows g(n'): h = 4*(quad&1)+reg, j = col0/8+ct*2+(quad>>1)
                const int hbase = 4 * (quad & 1);
                const int j     = (col0 >> 3) + ct * 2 + (quad >> 1);
                float o0 = fmaf(bias[(hbase + 0) * 64 + j], bs, acc[0]);
                float o1 = fmaf(bias[(hbase + 1) * 64 + j], bs, acc[1]);
                float o2 = fmaf(bias[(hbase + 2) * 64 + j], bs, acc[2]);
                float o3 = fmaf(bias[(hbase + 3) * 64 + j], bs, acc[3]);
                p0.h = pk(o0, o1);                 // h-pair 2*(quad&1)
                p1.h = pk(o2, o3);                 // h-pair 2*(quad&1)+1
                if (m < TPB) {
                    uint2 st; st.x = p0.u; st.y = p1.u;
                    *(uint2*)&dstT[m * TOKPAD + j * 4 + 2 * (quad & 1)] = st;
                }
            } else {
                // natural: cols nn..nn+3 = v[h][jj..jj+3]
                const int nn = col0 + ct * 16 + quad * 4;
                const int h  = nn >> 6;
                const int jj = nn & 63;
                const float4 b4 = *(const float4*)&bias[nn];
                p0.h = pk(acc[0] + b4.x, acc[1] + b4.y);
                p1.h = pk(acc[2] + b4.z, acc[3] + b4.w);
                if (m < TPB) {
                    uint2 st; st.x = p0.u; st.y = p1.u;
                    *(uint2*)&dstT[m * TOKPAD + h * 32 + (jj >> 1)] = st;
                }
            }
        }
    }
    __syncthreads();   // producer (all waves write all 8 tokens) -> consumer

    __fp16* resL = (__fp16*)qT;            // res overlay: row stride 520 halves

    // ---- consumer: each wave runs 2 tokens serially
    for (int i = 0; i < 2; ++i) {
        const int t = w * 2 + i;

        union { half8 h8; half2v h2[4]; } uq;
        uq.h8 = *(const half8*)&qT[t * TOKPAD + lane * 4];  // qT row t dead after this

        // dot row (pre-scaled by am1/8 via Wq): row[j] = sum_h q[h][lane]*k[h][j]
        float row[64];
        #pragma unroll
        for (int j = 0; j < 64; j += 2) {
            union { half8 h8; half2v h2[4]; } u0, u1;
            u0.h8 = *(const half8*)&kT[t * TOKPAD + j * 4];        // broadcast b128
            u1.h8 = *(const half8*)&kT[t * TOKPAD + (j + 1) * 4];
            float d0 = dot2(uq.h2[0], u0.h2[0], 0.0f);
            float d1 = dot2(uq.h2[0], u1.h2[0], 0.0f);
            d0 = dot2(uq.h2[1], u0.h2[1], d0);
            d1 = dot2(uq.h2[1], u1.h2[1], d1);
            d0 = dot2(uq.h2[2], u0.h2[2], d0);
            d1 = dot2(uq.h2[2], u1.h2[2], d1);
            d0 = dot2(uq.h2[3], u0.h2[3], d0);
            d1 = dot2(uq.h2[3], u1.h2[3], d1);
            row[j] = d0; row[j + 1] = d1;
        }

        // max over 64 (4-way ILP)
        float m0 = fmaxf(row[0], row[1]);
        float m1 = fmaxf(row[2], row[3]);
        float m2 = fmaxf(row[4], row[5]);
        float m3 = fmaxf(row[6], row[7]);
        #pragma unroll
        for (int j = 8; j < 64; j += 8) {
            m0 = fmaxf(m0, fmaxf(row[j + 0], row[j + 1]));
            m1 = fmaxf(m1, fmaxf(row[j + 2], row[j + 3]));
            m2 = fmaxf(m2, fmaxf(row[j + 4], row[j + 5]));
            m3 = fmaxf(m3, fmaxf(row[j + 6], row[j + 7]));
        }
        const float mx = fmaxf(fmaxf(m0, m1), fmaxf(m2, m3));

        float tau_lo = mx - 1.0f;                         // _gp(1, alpha) = 1
        const float tau_hi = mx - exp2f(-6.0f * am1);     // (1/64)^am1
        float dm = tau_hi - tau_lo;
        float inv_sum;
        half2v p2[32];

        if (am1 == 0.5f) {
            // upper clamp is dead: tau >= mx-1 always => z = row-tau <= 1.
            // 6 bisection steps, f >= 0 test (f_lo >= 0 provably)
            #pragma unroll
            for (int it = 0; it < 6; ++it) {
                dm *= 0.5f;
                const float tau_m = tau_lo + dm;
                float f0 = -1.0f, f1 = 0.0f, f2 = 0.0f, f3 = 0.0f;
                #pragma unroll
                for (int j = 0; j < 64; j += 4) {
                    const float a0 = fmaxf(row[j + 0] - tau_m, 0.0f);
                    const float a1 = fmaxf(row[j + 1] - tau_m, 0.0f);
                    const float a2 = fmaxf(row[j + 2] - tau_m, 0.0f);
                    const float a3 = fmaxf(row[j + 3] - tau_m, 0.0f);
                    f0 = fmaf(a0, a0, f0); f1 = fmaf(a1, a1, f1);
                    f2 = fmaf(a2, a2, f2); f3 = fmaf(a3, a3, f3);
                }
                const float f = (f0 + f1) + (f2 + f3);
                tau_lo = (f >= 0.0f) ? tau_m : tau_lo;
            }
            // 2 guarded Newton steps (tau += max(f,0)/(2s); never moves if f<0)
            float tau = tau_lo;
            #pragma unroll
            for (int it = 0; it < 2; ++it) {
                float f0 = -1.0f, f1 = 0.0f, f2 = 0.0f, f3 = 0.0f;
                float s0 = 0.0f, s1 = 0.0f, s2 = 0.0f, s3 = 0.0f;
                #pragma unroll
                for (int j = 0; j < 64; j += 4) {
                    const float a0 = fmaxf(row[j + 0] - tau, 0.0f);
                    const float a1 = fmaxf(row[j + 1] - tau, 0.0f);
                    const float a2 = fmaxf(row[j + 2] - tau, 0.0f);
                    const float a3 = fmaxf(row[j + 3] - tau, 0.0f);
                    f0 = fmaf(a0, a0, f0); f1 = fmaf(a1, a1, f1);
                    f2 = fmaf(a2, a2, f2); f3 = fmaf(a3, a3, f3);
                    s0 += a0; s1 += a1; s2 += a2; s3 += a3;
                }
                const float f = (f0 + f1) + (f2 + f3);
                const float s = ((s0 + s1) + (s2 + s3)) + 1e-20f;  // s >= 1/8
                tau = tau + fmaxf(f, 0.0f) * __builtin_amdgcn_rcpf(s + s);
            }
            // final p (unnormalized) + sum; normalization folded into av
            float s0 = 0.0f, s1 = 0.0f;
            #pragma unroll
            for (int j = 0; j < 64; j += 2) {
                float a0 = fmaxf(row[j + 0] - tau, 0.0f);
                float a1 = fmaxf(row[j + 1] - tau, 0.0f);
                a0 *= a0; a1 *= a1;
                row[j + 0] = a0; row[j + 1] = a1;
                s0 += a0; s1 += a1;
            }
            inv_sum = 1.0f / (s0 + s1);
        } else {
            // faithful general-alpha path (unused for this problem's alpha=1.5)
            const float inv = 1.0f / am1;
            float tau_m = tau_lo;
            float f_lo = -1.0f;
            #pragma unroll
            for (int j = 0; j < 64; ++j) f_lo += pgen(row[j] - tau_lo, inv);
            for (int it = 0; it < 30; ++it) {
                dm *= 0.5f;
                tau_m = tau_lo + dm;
                float f = -1.0f;
                #pragma unroll
                for (int j = 0; j < 64; ++j) f += pgen(row[j] - tau_m, inv);
                tau_lo = (f * f_lo >= 0.0f) ? tau_m : tau_lo;
            }
            float s = 0.0f;
            #pragma unroll
            for (int j = 0; j < 64; ++j) {
                const float pm = pgen(row[j] - tau_m, inv);
                row[j] = pm;
                s += pm;
            }
            inv_sum = 1.0f / s;
        }

        // av: res[h][lane] = inv_sum * sum_j p[j] * v[h][j]  via fp16 dot2
        #pragma unroll
        for (int ii = 0; ii < 32; ++ii) p2[ii] = pk(row[2 * ii], row[2 * ii + 1]);

        float acc[8];
        #pragma unroll
        for (int h = 0; h < 8; ++h) {
            float a0 = 0.0f, a1 = 0.0f;
            #pragma unroll
            for (int jc = 0; jc < 8; ++jc) {
                union { half8 h8; half2v h2[4]; } u;
                u.h8 = *(const half8*)&vT[t * TOKPAD + h * 32 + jc * 4];
                a0 = dot2(p2[jc * 4 + 0], u.h2[0], a0);
                a1 = dot2(p2[jc * 4 + 1], u.h2[1], a1);
                a0 = dot2(p2[jc * 4 + 2], u.h2[2], a0);
                a1 = dot2(p2[jc * 4 + 3], u.h2[3], a1);
            }
            acc[h] = a0 + a1;
        }
        // res -> LDS overlay of qT row t (wave-private row; same fp16 cast
        // as before => identical values feed the out MFMA)
        #pragma unroll
        for (int h = 0; h < 8; ++h)
            resL[t * 520 + h * 64 + lane] = (__fp16)(acc[h] * inv_sum);
    }
    __syncthreads();   // all 8 tokens' res in LDS -> out phase

    // ---- out phase: wave w computes out cols w*16..w*16+15 for 8 tokens.
    // B-frag token column m; cols m>=8 duplicate token m&7 (discarded).
    {
        floatx4 oacc = (floatx4){0.f, 0.f, 0.f, 0.f};
        const int mm = m & 7;
        const __fp16* rrow = resL + (size_t)mm * 520 + quad * 8;  // token mm
        const __fp16* wrow = wuh + (size_t)(w * 16 + m) * HHE + quad * 8;
        #pragma unroll
        for (int kc = 0; kc < 16; ++kc) {              // K=512 in 32-chunks
            const half8 bf = *(const half8*)(rrow + kc * 32);
            const half8 af = *(const half8*)(wrow + kc * 32);
            oacc = __builtin_amdgcn_mfma_f32_16x16x32_f16(af, bf, oacc, 0, 0, 0);
        }
        if (m < TPB) {
            const int tok = tok0 + m;
            const int col = w * 16 + quad * 4;         // 4 consecutive out cols
            const float4 b4 = *(const float4*)&bu[col];
            float4 o;
            o.x = oacc[0] + b4.x;
            o.y = oacc[1] + b4.y;
            o.z = oacc[2] + b4.z;
            o.w = oacc[3] + b4.w;
            *(float4*)&out[(size_t)tok * 64 + col] = o;
        }
    }
}

// ---------------------------------------------------------------------------
extern "C" void kernel_launch(void* const* d_in, const int* in_sizes, int n_in,
                              void* d_out, int out_size, void* d_ws, size_t ws_size,
                              hipStream_t stream)
{
    const float* x     = (const float*)d_in[0];
    const float* alpha = (const float*)d_in[1];
    const float* Wk    = (const float*)d_in[2];
    const float* bk    = (const float*)d_in[3];
    const float* Wq    = (const float*)d_in[4];
    const float* bq    = (const float*)d_in[5];
    const float* Wv    = (const float*)d_in[6];
    const float* bv    = (const float*)d_in[7];
    const float* Wu    = (const float*)d_in[8];
    const float* bu    = (const float*)d_in[9];
    float* out = (float*)d_out;

    // workspace (fp16 units): wkh/wqh/wvh/wuh 32768 each
    __fp16* wkh  = (__fp16*)d_ws;
    __fp16* wqh  = wkh + (size_t)HHE * EDIM;
    __fp16* wvh  = wqh + (size_t)HHE * EDIM;
    __fp16* wuh  = wvh + (size_t)HHE * EDIM;

    cvt_fp16_kernel<<<dim3(16, 4), 256, 0, stream>>>(
        Wk, Wq, Wv, Wu, wkh, wqh, wvh, wuh, alpha);
    qkv_attn_out_kernel<<<NTOK / TPB, 256, 0, stream>>>(
        x, wkh, bk, wqh, bq, wvh, bv, wuh, bu, out, alpha);
}

// Round 5
// 158.293 us; speedup vs baseline: 1.1541x; 1.1541x over previous
//
#include <hip/hip_runtime.h>
#include <math.h>

// Problem constants (b=8, c=2048, e=64, h=8)
#define NTOK 16384
#define EDIM 64
#define HHE  512   // h*e
#define TPB  16    // tokens per block (R21: reverted to 16 — TPB=8 regressed,
                   // residency is NOT LDS-capped; see R20 post-mortem)
#define TOKPAD 260 // half2 slots per token row: 256 + 4 pad (16B-aligned rows)

typedef _Float16 half8 __attribute__((ext_vector_type(8)));   // MFMA operand type
typedef __fp16   half2v __attribute__((ext_vector_type(2)));  // builtin V2h type
typedef float    floatx4 __attribute__((ext_vector_type(4)));

__device__ __forceinline__ half8 cvt8(const float4 a, const float4 b) {
    half8 h;
    h[0] = (_Float16)a.x; h[1] = (_Float16)a.y;
    h[2] = (_Float16)a.z; h[3] = (_Float16)a.w;
    h[4] = (_Float16)b.x; h[5] = (_Float16)b.y;
    h[6] = (_Float16)b.z; h[7] = (_Float16)b.w;
    return h;
}

// fp32 += half2 . half2 (v_dot2_f32_f16); float fallback if builtin missing
__device__ __forceinline__ float dot2(half2v a, half2v b, float c) {
#if __has_builtin(__builtin_amdgcn_fdot2)
    return __builtin_amdgcn_fdot2(a, b, c, false);
#else
    return fmaf((float)a[0], (float)b[0], fmaf((float)a[1], (float)b[1], c));
#endif
}
__device__ __forceinline__ half2v pk(float x, float y) {
    return __builtin_amdgcn_cvt_pkrtz(x, y);   // v_cvt_pkrtz_f16_f32 (V2h)
}
union h2u { half2v h; unsigned int u; };

// packed fp16 max (v_pk_max_f16) — genuine 2x-rate on CDNA
__device__ __forceinline__ half2v pkmax(half2v a, half2v b) {
#if __has_builtin(__builtin_elementwise_max)
    return __builtin_elementwise_max(a, b);
#else
    half2v d;
    asm("v_pk_max_f16 %0, %1, %2" : "=v"(d) : "v"(a), "v"(b));
    return d;
#endif
}

__device__ __forceinline__ float pgen(float z, float inv) {
    return z > 0.0f ? exp2f(inv * log2f(fmaxf(z, 1e-30f))) : 0.0f;
}

// ---------------------------------------------------------------------------
// Kernel 0: fp32 -> fp16 (RTN cast) for the 4 weight matrices only.
// Wq is pre-scaled by (alpha-1)/sqrt(e) = am1*0.125 so the score scale
// vanishes from the consumer hot loop. x is converted inline in kernel 1.
// All 4 matrices are 32768 elems -> grid (16,4), no bounds check needed.
// ---------------------------------------------------------------------------
__global__ __launch_bounds__(256) void cvt_fp16_kernel(
    const float* __restrict__ Wk, const float* __restrict__ Wq,
    const float* __restrict__ Wv, const float* __restrict__ Wu,
    __fp16* __restrict__ wkh, __fp16* __restrict__ wqh,
    __fp16* __restrict__ wvh, __fp16* __restrict__ wuh,
    const float* alpha_p)
{
    const int z = blockIdx.y;
    const float* src; __fp16* dst;
    float s = 1.0f;
    if      (z == 0) { src = Wk; dst = wkh; }
    else if (z == 1) { src = Wq; dst = wqh; s = (alpha_p[0] - 1.0f) * 0.125f; }
    else if (z == 2) { src = Wv; dst = wvh; }
    else             { src = Wu; dst = wuh; }
    const int idx = (blockIdx.x * 256 + threadIdx.x) * 8;
    float4 a = *(const float4*)(src + idx);
    float4 b = *(const float4*)(src + idx + 4);
    a.x *= s; a.y *= s; a.z *= s; a.w *= s;
    b.x *= s; b.y *= s; b.z *= s; b.w *= s;
    *(half8*)(dst + idx) = cvt8(a, b);
}

// ---------------------------------------------------------------------------
// Kernel 1: FULLY FUSED qkv + entmax-attention + output projection.
// R21: TPB back to 16 (R20's TPB=8 regressed: residency stuck ~2.3
// blocks/CU regardless of LDS, producer overhead doubled for nothing).
// New: 6 bisection passes run in PACKED FP16 (v_pk_add/max/fma_f16,
// true 2x rate) — bisection only needs sign(f); fp16 tau-resolution
// (~5e-4) far exceeds what 6 bisections achieve (0.014). The 2 fp32
// Newton steps + fp32 final pass are unchanged and restore fp32
// convergence, so accuracy is preserved. ~-20% VALU insts/token.
// ---------------------------------------------------------------------------
__global__ __launch_bounds__(256) void qkv_attn_out_kernel(
    const float* __restrict__ x,
    const __fp16* __restrict__ wkh, const float* __restrict__ bk,
    const __fp16* __restrict__ wqh, const float* __restrict__ bq,
    const __fp16* __restrict__ wvh, const float* __restrict__ bv,
    const __fp16* __restrict__ wuh, const float* __restrict__ bu,
    float* __restrict__ out, const float* alpha_p)
{
    __shared__ __align__(16) half2v qT[TPB * TOKPAD];  // [tok][i*4+hpair] -> res overlay
    __shared__ __align__(16) half2v kT[TPB * TOKPAD];  // [tok][j*4 + hpair]
    __shared__ __align__(16) half2v vT[TPB * TOKPAD];  // [tok][h*32 + jpair]

    const int tid  = threadIdx.x;
    const int lane = tid & 63;
    const int w    = tid >> 6;
    const int tok0 = blockIdx.x * TPB;

    const int m    = lane & 15;            // token (B row)
    const int quad = lane >> 4;

    const float alpha = alpha_p[0];
    const float am1   = alpha - 1.0f;
    const float s_q   = am1 * 0.125f;      // matches cvt kernel's Wq scale

    // ---- x B-fragments: fp32 load + RTN cast (identical to old cvt path)
    const float* xrow = x + (size_t)(tok0 + m) * EDIM + quad * 8;
    half8 bfr[2];
    {
        const float4 a0 = *(const float4*)(xrow);
        const float4 a1 = *(const float4*)(xrow + 4);
        const float4 a2 = *(const float4*)(xrow + 32);
        const float4 a3 = *(const float4*)(xrow + 36);
        bfr[0] = cvt8(a0, a1);
        bfr[1] = cvt8(a2, a3);
    }

    // ---- producer: units w*3 .. w*3+2; unit = z*4 + ntile
    #pragma unroll
    for (int uu = 0; uu < 3; ++uu) {
        const int unit = w * 3 + uu;
        const int z    = unit >> 2;            // 0=k, 1=q, 2=v
        const int col0 = (unit & 3) * 128;
        const __fp16* W   = (z == 0) ? wkh : (z == 1) ? wqh : wvh;
        const float* bias = (z == 0) ? bk : (z == 1) ? bq : bv;
        half2v* dstT      = (z == 0) ? kT : (z == 1) ? qT : vT;
        // q path: W pre-scaled; bias scaled here via exact fmaf (bs=1 for k)
        const float bs    = (z == 1) ? s_q : 1.0f;

        #pragma unroll
        for (int ct = 0; ct < 8; ++ct) {
            const int n = col0 + ct * 16 + m;
            // permuted W row for q/k; natural for v
            const int grow = (z < 2) ? ((n & 7) * 64 + (n >> 3)) : n;
            const __fp16* wrow = W + (size_t)grow * EDIM + quad * 8;
            floatx4 acc = (floatx4){0.f, 0.f, 0.f, 0.f};
            #pragma unroll
            for (int kc = 0; kc < 2; ++kc) {
                const half8 af = *(const half8*)(wrow + kc * 32);  // direct fp16
                acc = __builtin_amdgcn_mfma_f32_16x16x32_f16(af, bfr[kc], acc, 0, 0, 0);
            }
            // lane's 4 regs = D rows quad*4+0..3, D col = m (token)
            h2u p0, p1;
            if (z < 2) {
                // output rows g(n'): h = 4*(quad&1)+reg, j = col0/8+ct*2+(quad>>1)
                const int hbase = 4 * (quad & 1);
                const int j     = (col0 >> 3) + ct * 2 + (quad >> 1);
                float o0 = fmaf(bias[(hbase + 0) * 64 + j], bs, acc[0]);
                float o1 = fmaf(bias[(hbase + 1) * 64 + j], bs, acc[1]);
                float o2 = fmaf(bias[(hbase + 2) * 64 + j], bs, acc[2]);
                float o3 = fmaf(bias[(hbase + 3) * 64 + j], bs, acc[3]);
                p0.h = pk(o0, o1);                 // h-pair 2*(quad&1)
                p1.h = pk(o2, o3);                 // h-pair 2*(quad&1)+1
                uint2 st; st.x = p0.u; st.y = p1.u;
                *(uint2*)&dstT[m * TOKPAD + j * 4 + 2 * (quad & 1)] = st;
            } else {
                // natural: cols nn..nn+3 = v[h][jj..jj+3]
                const int nn = col0 + ct * 16 + quad * 4;
                const int h  = nn >> 6;
                const int jj = nn & 63;
                const float4 b4 = *(const float4*)&bias[nn];
                p0.h = pk(acc[0] + b4.x, acc[1] + b4.y);
                p1.h = pk(acc[2] + b4.z, acc[3] + b4.w);
                uint2 st; st.x = p0.u; st.y = p1.u;
                *(uint2*)&dstT[m * TOKPAD + h * 32 + (jj >> 1)] = st;
            }
        }
    }
    __syncthreads();   // producer (all waves write all 16 tokens) -> consumer

    __fp16* resL = (__fp16*)qT;            // res overlay: row stride 520 halves

    // ---- consumer: each wave runs 4 tokens serially
    for (int i = 0; i < 4; ++i) {
        const int t = w * 4 + i;

        union { half8 h8; half2v h2[4]; } uq;
        uq.h8 = *(const half8*)&qT[t * TOKPAD + lane * 4];  // qT row t dead after this

        // dot row (pre-scaled by am1/8 via Wq): row[j] = sum_h q[h][lane]*k[h][j]
        float row[64];
        #pragma unroll
        for (int j = 0; j < 64; j += 2) {
            union { half8 h8; half2v h2[4]; } u0, u1;
            u0.h8 = *(const half8*)&kT[t * TOKPAD + j * 4];        // broadcast b128
            u1.h8 = *(const half8*)&kT[t * TOKPAD + (j + 1) * 4];
            float d0 = dot2(uq.h2[0], u0.h2[0], 0.0f);
            float d1 = dot2(uq.h2[0], u1.h2[0], 0.0f);
            d0 = dot2(uq.h2[1], u0.h2[1], d0);
            d1 = dot2(uq.h2[1], u1.h2[1], d1);
            d0 = dot2(uq.h2[2], u0.h2[2], d0);
            d1 = dot2(uq.h2[2], u1.h2[2], d1);
            d0 = dot2(uq.h2[3], u0.h2[3], d0);
            d1 = dot2(uq.h2[3], u1.h2[3], d1);
            row[j] = d0; row[j + 1] = d1;
        }

        // max over 64 (4-way ILP)
        float m0 = fmaxf(row[0], row[1]);
        float m1 = fmaxf(row[2], row[3]);
        float m2 = fmaxf(row[4], row[5]);
        float m3 = fmaxf(row[6], row[7]);
        #pragma unroll
        for (int j = 8; j < 64; j += 8) {
            m0 = fmaxf(m0, fmaxf(row[j + 0], row[j + 1]));
            m1 = fmaxf(m1, fmaxf(row[j + 2], row[j + 3]));
            m2 = fmaxf(m2, fmaxf(row[j + 4], row[j + 5]));
            m3 = fmaxf(m3, fmaxf(row[j + 6], row[j + 7]));
        }
        const float mx = fmaxf(fmaxf(m0, m1), fmaxf(m2, m3));

        float tau_lo = mx - 1.0f;                         // _gp(1, alpha) = 1
        const float tau_hi = mx - exp2f(-6.0f * am1);     // (1/64)^am1
        float dm = tau_hi - tau_lo;
        float inv_sum;
        half2v p2[32];

        if (am1 == 0.5f) {
            // upper clamp is dead: tau >= mx-1 always => z = row-tau <= 1.
            // --- 6 bisection steps in PACKED FP16 (sign test only).
            // fp16 tau-resolution ~5e-4 << bisection's 0.014 target, so
            // no accuracy is ceded; fp32 Newton below restores the rest.
            half2v rowh[32];
            #pragma unroll
            for (int jj = 0; jj < 32; ++jj) rowh[jj] = pk(row[2 * jj], row[2 * jj + 1]);
            const half2v zero2 = {(_Float16)0.0f, (_Float16)0.0f};
            const half2v one2  = pk(1.0f, 1.0f);

            #pragma unroll
            for (int it = 0; it < 6; ++it) {
                dm *= 0.5f;
                const float tau_m = tau_lo + dm;
                const half2v nt2 = pk(-tau_m, -tau_m);
                half2v f0 = zero2, f1 = zero2, f2 = zero2, f3 = zero2;
                #pragma unroll
                for (int jj = 0; jj < 32; jj += 4) {
                    half2v a0 = pkmax(rowh[jj + 0] + nt2, zero2);
                    half2v a1 = pkmax(rowh[jj + 1] + nt2, zero2);
                    half2v a2 = pkmax(rowh[jj + 2] + nt2, zero2);
                    half2v a3 = pkmax(rowh[jj + 3] + nt2, zero2);
                    f0 = a0 * a0 + f0;     // v_pk_fma_f16 (contracted)
                    f1 = a1 * a1 + f1;
                    f2 = a2 * a2 + f2;
                    f3 = a3 * a3 + f3;
                }
                // pair-sums -> fp32 via v_dot2_f32_f16 with (1,1); init -1
                float fs = dot2(f0, one2, -1.0f);
                fs = dot2(f1, one2, fs);
                fs = dot2(f2, one2, fs);
                fs = dot2(f3, one2, fs);
                tau_lo = (fs >= 0.0f) ? tau_m : tau_lo;
            }
            // --- 2 guarded fp32 Newton steps (tau += max(f,0)/(2s))
            float tau = tau_lo;
            #pragma unroll
            for (int it = 0; it < 2; ++it) {
                float f0 = -1.0f, f1 = 0.0f, f2 = 0.0f, f3 = 0.0f;
                float s0 = 0.0f, s1 = 0.0f, s2 = 0.0f, s3 = 0.0f;
                #pragma unroll
                for (int j = 0; j < 64; j += 4) {
                    const float a0 = fmaxf(row[j + 0] - tau, 0.0f);
                    const float a1 = fmaxf(row[j + 1] - tau, 0.0f);
                    const float a2 = fmaxf(row[j + 2] - tau, 0.0f);
                    const float a3 = fmaxf(row[j + 3] - tau, 0.0f);
                    f0 = fmaf(a0, a0, f0); f1 = fmaf(a1, a1, f1);
                    f2 = fmaf(a2, a2, f2); f3 = fmaf(a3, a3, f3);
                    s0 += a0; s1 += a1; s2 += a2; s3 += a3;
                }
                const float f = (f0 + f1) + (f2 + f3);
                const float s = ((s0 + s1) + (s2 + s3)) + 1e-20f;  // s >= 1/8
                tau = tau + fmaxf(f, 0.0f) * __builtin_amdgcn_rcpf(s + s);
            }
            // final p (unnormalized, fp32) + sum; normalization folded into av
            float s0 = 0.0f, s1 = 0.0f;
            #pragma unroll
            for (int j = 0; j < 64; j += 2) {
                float a0 = fmaxf(row[j + 0] - tau, 0.0f);
                float a1 = fmaxf(row[j + 1] - tau, 0.0f);
                a0 *= a0; a1 *= a1;
                row[j + 0] = a0; row[j + 1] = a1;
                s0 += a0; s1 += a1;
            }
            inv_sum = 1.0f / (s0 + s1);
        } else {
            // faithful general-alpha path (unused for this problem's alpha=1.5)
            const float inv = 1.0f / am1;
            float tau_m = tau_lo;
            float f_lo = -1.0f;
            #pragma unroll
            for (int j = 0; j < 64; ++j) f_lo += pgen(row[j] - tau_lo, inv);
            for (int it = 0; it < 30; ++it) {
                dm *= 0.5f;
                tau_m = tau_lo + dm;
                float f = -1.0f;
                #pragma unroll
                for (int j = 0; j < 64; ++j) f += pgen(row[j] - tau_m, inv);
                tau_lo = (f * f_lo >= 0.0f) ? tau_m : tau_lo;
            }
            float s = 0.0f;
            #pragma unroll
            for (int j = 0; j < 64; ++j) {
                const float pm = pgen(row[j] - tau_m, inv);
                row[j] = pm;
                s += pm;
            }
            inv_sum = 1.0f / s;
        }

        // av: res[h][lane] = inv_sum * sum_j p[j] * v[h][j]  via fp16 dot2
        #pragma unroll
        for (int ii = 0; ii < 32; ++ii) p2[ii] = pk(row[2 * ii], row[2 * ii + 1]);

        float acc[8];
        #pragma unroll
        for (int h = 0; h < 8; ++h) {
            float a0 = 0.0f, a1 = 0.0f;
            #pragma unroll
            for (int jc = 0; jc < 8; ++jc) {
                union { half8 h8; half2v h2[4]; } u;
                u.h8 = *(const half8*)&vT[t * TOKPAD + h * 32 + jc * 4];
                a0 = dot2(p2[jc * 4 + 0], u.h2[0], a0);
                a1 = dot2(p2[jc * 4 + 1], u.h2[1], a1);
                a0 = dot2(p2[jc * 4 + 2], u.h2[2], a0);
                a1 = dot2(p2[jc * 4 + 3], u.h2[3], a1);
            }
            acc[h] = a0 + a1;
        }
        // res -> LDS overlay of qT row t (wave-private row; same fp16 cast
        // as before => identical values feed the out MFMA)
        #pragma unroll
        for (int h = 0; h < 8; ++h)
            resL[t * 520 + h * 64 + lane] = (__fp16)(acc[h] * inv_sum);
    }
    __syncthreads();   // all 16 tokens' res in LDS -> out phase

    // ---- out phase: wave w computes out cols w*16..w*16+15 for 16 tokens.
    {
        floatx4 oacc = (floatx4){0.f, 0.f, 0.f, 0.f};
        const __fp16* rrow = resL + (size_t)m * 520 + quad * 8;   // token m
        const __fp16* wrow = wuh + (size_t)(w * 16 + m) * HHE + quad * 8;
        #pragma unroll
        for (int kc = 0; kc < 16; ++kc) {              // K=512 in 32-chunks
            const half8 bf = *(const half8*)(rrow + kc * 32);
            const half8 af = *(const half8*)(wrow + kc * 32);
            oacc = __builtin_amdgcn_mfma_f32_16x16x32_f16(af, bf, oacc, 0, 0, 0);
        }
        const int tok = tok0 + m;
        const int col = w * 16 + quad * 4;             // 4 consecutive out cols
        const float4 b4 = *(const float4*)&bu[col];
        float4 o;
        o.x = oacc[0] + b4.x;
        o.y = oacc[1] + b4.y;
        o.z = oacc[2] + b4.z;
        o.w = oacc[3] + b4.w;
        *(float4*)&out[(size_t)tok * 64 + col] = o;
    }
}

// ---------------------------------------------------------------------------
extern "C" void kernel_launch(void* const* d_in, const int* in_sizes, int n_in,
                              void* d_out, int out_size, void* d_ws, size_t ws_size,
                              hipStream_t stream)
{
    const float* x     = (const float*)d_in[0];
    const float* alpha = (const float*)d_in[1];
    const float* Wk    = (const float*)d_in[2];
    const float* bk    = (const float*)d_in[3];
    const float* Wq    = (const float*)d_in[4];
    const float* bq    = (const float*)d_in[5];
    const float* Wv    = (const float*)d_in[6];
    const float* bv    = (const float*)d_in[7];
    const float* Wu    = (const float*)d_in[8];
    const float* bu    = (const float*)d_in[9];
    float* out = (float*)d_out;

    // workspace (fp16 units): wkh/wqh/wvh/wuh 32768 each
    __fp16* wkh  = (__fp16*)d_ws;
    __fp16* wqh  = wkh + (size_t)HHE * EDIM;
    __fp16* wvh  = wqh + (size_t)HHE * EDIM;
    __fp16* wuh  = wvh + (size_t)HHE * EDIM;

    cvt_fp16_kernel<<<dim3(16, 4), 256, 0, stream>>>(
        Wk, Wq, Wv, Wu, wkh, wqh, wvh, wuh, alpha);
    qkv_attn_out_kernel<<<NTOK / TPB, 256, 0, stream>>>(
        x, wkh, bk, wqh, bq, wvh, bv, wuh, bu, out, alpha);
}

// Round 6
// 157.605 us; speedup vs baseline: 1.1592x; 1.0044x over previous
//
#include <hip/hip_runtime.h>
#include <math.h>

// Problem constants (b=8, c=2048, e=64, h=8)
#define NTOK 16384
#define EDIM 64
#define HHE  512   // h*e
#define TPB  16    // tokens per block (TPB=8 falsified in R20: residency is
                   // not LDS-capped; producer overhead doubled for nothing)
#define TOKPAD 260 // half2 slots per token row: 256 + 4 pad (16B-aligned rows)

typedef _Float16 half8 __attribute__((ext_vector_type(8)));   // MFMA operand type
typedef __fp16   half2v __attribute__((ext_vector_type(2)));  // builtin V2h type
typedef _Float16 f16x2 __attribute__((ext_vector_type(2)));   // NATIVE-arith half pair
typedef float    floatx4 __attribute__((ext_vector_type(4)));

__device__ __forceinline__ half8 cvt8(const float4 a, const float4 b) {
    half8 h;
    h[0] = (_Float16)a.x; h[1] = (_Float16)a.y;
    h[2] = (_Float16)a.z; h[3] = (_Float16)a.w;
    h[4] = (_Float16)b.x; h[5] = (_Float16)b.y;
    h[6] = (_Float16)b.z; h[7] = (_Float16)b.w;
    return h;
}

// fp32 += half2 . half2 (v_dot2_f32_f16); float fallback if builtin missing
__device__ __forceinline__ float dot2(half2v a, half2v b, float c) {
#if __has_builtin(__builtin_amdgcn_fdot2)
    return __builtin_amdgcn_fdot2(a, b, c, false);
#else
    return fmaf((float)a[0], (float)b[0], fmaf((float)a[1], (float)b[1], c));
#endif
}
__device__ __forceinline__ half2v pk(float x, float y) {
    return __builtin_amdgcn_cvt_pkrtz(x, y);   // v_cvt_pkrtz_f16_f32 (V2h)
}
union h2u { half2v h; unsigned int u; };
union h2f { half2v h; f16x2 f; unsigned int u; };   // bitcast __fp16v2 <-> _Float16v2

// v_pk_max_f16 on the NATIVE _Float16 vector type (no float promotion)
__device__ __forceinline__ f16x2 pmax16(f16x2 a, f16x2 b) {
    return __builtin_elementwise_max(a, b);
}

__device__ __forceinline__ float pgen(float z, float inv) {
    return z > 0.0f ? exp2f(inv * log2f(fmaxf(z, 1e-30f))) : 0.0f;
}

// ---------------------------------------------------------------------------
// Kernel 0: fp32 -> fp16 (RTN cast) for the 4 weight matrices only.
// Wq is pre-scaled by (alpha-1)/sqrt(e) = am1*0.125 so the score scale
// vanishes from the consumer hot loop. x is converted inline in kernel 1.
// ---------------------------------------------------------------------------
__global__ __launch_bounds__(256) void cvt_fp16_kernel(
    const float* __restrict__ Wk, const float* __restrict__ Wq,
    const float* __restrict__ Wv, const float* __restrict__ Wu,
    __fp16* __restrict__ wkh, __fp16* __restrict__ wqh,
    __fp16* __restrict__ wvh, __fp16* __restrict__ wuh,
    const float* alpha_p)
{
    const int z = blockIdx.y;
    const float* src; __fp16* dst;
    float s = 1.0f;
    if      (z == 0) { src = Wk; dst = wkh; }
    else if (z == 1) { src = Wq; dst = wqh; s = (alpha_p[0] - 1.0f) * 0.125f; }
    else if (z == 2) { src = Wv; dst = wvh; }
    else             { src = Wu; dst = wuh; }
    const int idx = (blockIdx.x * 256 + threadIdx.x) * 8;
    float4 a = *(const float4*)(src + idx);
    float4 b = *(const float4*)(src + idx + 4);
    a.x *= s; a.y *= s; a.z *= s; a.w *= s;
    b.x *= s; b.y *= s; b.z *= s; b.w *= s;
    *(half8*)(dst + idx) = cvt8(a, b);
}

// ---------------------------------------------------------------------------
// Kernel 1: FULLY FUSED qkv + entmax-attention + output projection.
// R22: the 6 bisection passes + Newton step 1 run in packed fp16 on
// _Float16 ext-vectors (v_pk_add/max/fma_f16, true 2x rate). R21's
// attempt used __fp16 vectors, whose arithmetic clang promotes through
// fp32 — counters proved it was a no-op (VALU busy-time identical).
// Newton step 2 + the final p pass stay fp32, restoring tau to ~1e-5:
// accuracy class unchanged. Bisection needs only sign(f); fp16 tau
// resolution (~5e-4) far exceeds bisection's 0.014 target. Newton1 in
// fp16 lands within ~1e-3 (f/s fp16-accum error ~< 1e-3 of the step),
// which fp32 Newton2 then squares down to ~4e-6.
// ---------------------------------------------------------------------------
__global__ __launch_bounds__(256) void qkv_attn_out_kernel(
    const float* __restrict__ x,
    const __fp16* __restrict__ wkh, const float* __restrict__ bk,
    const __fp16* __restrict__ wqh, const float* __restrict__ bq,
    const __fp16* __restrict__ wvh, const float* __restrict__ bv,
    const __fp16* __restrict__ wuh, const float* __restrict__ bu,
    float* __restrict__ out, const float* alpha_p)
{
    __shared__ __align__(16) half2v qT[TPB * TOKPAD];  // [tok][i*4+hpair] -> res overlay
    __shared__ __align__(16) half2v kT[TPB * TOKPAD];  // [tok][j*4 + hpair]
    __shared__ __align__(16) half2v vT[TPB * TOKPAD];  // [tok][h*32 + jpair]

    const int tid  = threadIdx.x;
    const int lane = tid & 63;
    const int w    = tid >> 6;
    const int tok0 = blockIdx.x * TPB;

    const int m    = lane & 15;            // token (B row)
    const int quad = lane >> 4;

    const float alpha = alpha_p[0];
    const float am1   = alpha - 1.0f;
    const float s_q   = am1 * 0.125f;      // matches cvt kernel's Wq scale

    // ---- x B-fragments: fp32 load + RTN cast (identical to old cvt path)
    const float* xrow = x + (size_t)(tok0 + m) * EDIM + quad * 8;
    half8 bfr[2];
    {
        const float4 a0 = *(const float4*)(xrow);
        const float4 a1 = *(const float4*)(xrow + 4);
        const float4 a2 = *(const float4*)(xrow + 32);
        const float4 a3 = *(const float4*)(xrow + 36);
        bfr[0] = cvt8(a0, a1);
        bfr[1] = cvt8(a2, a3);
    }

    // ---- producer: units w*3 .. w*3+2; unit = z*4 + ntile
    #pragma unroll
    for (int uu = 0; uu < 3; ++uu) {
        const int unit = w * 3 + uu;
        const int z    = unit >> 2;            // 0=k, 1=q, 2=v
        const int col0 = (unit & 3) * 128;
        const __fp16* W   = (z == 0) ? wkh : (z == 1) ? wqh : wvh;
        const float* bias = (z == 0) ? bk : (z == 1) ? bq : bv;
        half2v* dstT      = (z == 0) ? kT : (z == 1) ? qT : vT;
        // q path: W pre-scaled; bias scaled here via exact fmaf (bs=1 for k)
        const float bs    = (z == 1) ? s_q : 1.0f;

        #pragma unroll
        for (int ct = 0; ct < 8; ++ct) {
            const int n = col0 + ct * 16 + m;
            // permuted W row for q/k; natural for v
            const int grow = (z < 2) ? ((n & 7) * 64 + (n >> 3)) : n;
            const __fp16* wrow = W + (size_t)grow * EDIM + quad * 8;
            floatx4 acc = (floatx4){0.f, 0.f, 0.f, 0.f};
            #pragma unroll
            for (int kc = 0; kc < 2; ++kc) {
                const half8 af = *(const half8*)(wrow + kc * 32);  // direct fp16
                acc = __builtin_amdgcn_mfma_f32_16x16x32_f16(af, bfr[kc], acc, 0, 0, 0);
            }
            // lane's 4 regs = D rows quad*4+0..3, D col = m (token)
            h2u p0, p1;
            if (z < 2) {
                // output rows g(n'): h = 4*(quad&1)+reg, j = col0/8+ct*2+(quad>>1)
                const int hbase = 4 * (quad & 1);
                const int j     = (col0 >> 3) + ct * 2 + (quad >> 1);
                float o0 = fmaf(bias[(hbase + 0) * 64 + j], bs, acc[0]);
                float o1 = fmaf(bias[(hbase + 1) * 64 + j], bs, acc[1]);
                float o2 = fmaf(bias[(hbase + 2) * 64 + j], bs, acc[2]);
                float o3 = fmaf(bias[(hbase + 3) * 64 + j], bs, acc[3]);
                p0.h = pk(o0, o1);                 // h-pair 2*(quad&1)
                p1.h = pk(o2, o3);                 // h-pair 2*(quad&1)+1
                uint2 st; st.x = p0.u; st.y = p1.u;
                *(uint2*)&dstT[m * TOKPAD + j * 4 + 2 * (quad & 1)] = st;
            } else {
                // natural: cols nn..nn+3 = v[h][jj..jj+3]
                const int nn = col0 + ct * 16 + quad * 4;
                const int h  = nn >> 6;
                const int jj = nn & 63;
                const float4 b4 = *(const float4*)&bias[nn];
                p0.h = pk(acc[0] + b4.x, acc[1] + b4.y);
                p1.h = pk(acc[2] + b4.z, acc[3] + b4.w);
                uint2 st; st.x = p0.u; st.y = p1.u;
                *(uint2*)&dstT[m * TOKPAD + h * 32 + (jj >> 1)] = st;
            }
        }
    }
    __syncthreads();   // producer (all waves write all 16 tokens) -> consumer

    __fp16* resL = (__fp16*)qT;            // res overlay: row stride 520 halves

    // ---- consumer: each wave runs 4 tokens serially
    for (int i = 0; i < 4; ++i) {
        const int t = w * 4 + i;

        union { half8 h8; half2v h2[4]; } uq;
        uq.h8 = *(const half8*)&qT[t * TOKPAD + lane * 4];  // qT row t dead after this

        // dot row (pre-scaled by am1/8 via Wq): row[j] = sum_h q[h][lane]*k[h][j]
        float row[64];
        #pragma unroll
        for (int j = 0; j < 64; j += 2) {
            union { half8 h8; half2v h2[4]; } u0, u1;
            u0.h8 = *(const half8*)&kT[t * TOKPAD + j * 4];        // broadcast b128
            u1.h8 = *(const half8*)&kT[t * TOKPAD + (j + 1) * 4];
            float d0 = dot2(uq.h2[0], u0.h2[0], 0.0f);
            float d1 = dot2(uq.h2[0], u1.h2[0], 0.0f);
            d0 = dot2(uq.h2[1], u0.h2[1], d0);
            d1 = dot2(uq.h2[1], u1.h2[1], d1);
            d0 = dot2(uq.h2[2], u0.h2[2], d0);
            d1 = dot2(uq.h2[2], u1.h2[2], d1);
            d0 = dot2(uq.h2[3], u0.h2[3], d0);
            d1 = dot2(uq.h2[3], u1.h2[3], d1);
            row[j] = d0; row[j + 1] = d1;
        }

        // max over 64 (4-way ILP, fp32 — keeps bracket guarantee exact)
        float m0 = fmaxf(row[0], row[1]);
        float m1 = fmaxf(row[2], row[3]);
        float m2 = fmaxf(row[4], row[5]);
        float m3 = fmaxf(row[6], row[7]);
        #pragma unroll
        for (int j = 8; j < 64; j += 8) {
            m0 = fmaxf(m0, fmaxf(row[j + 0], row[j + 1]));
            m1 = fmaxf(m1, fmaxf(row[j + 2], row[j + 3]));
            m2 = fmaxf(m2, fmaxf(row[j + 4], row[j + 5]));
            m3 = fmaxf(m3, fmaxf(row[j + 6], row[j + 7]));
        }
        const float mx = fmaxf(fmaxf(m0, m1), fmaxf(m2, m3));

        float tau_lo = mx - 1.0f;                         // _gp(1, alpha) = 1
        const float tau_hi = mx - exp2f(-6.0f * am1);     // (1/64)^am1
        float dm = tau_hi - tau_lo;
        float inv_sum;
        half2v p2[32];

        if (am1 == 0.5f) {
            // upper clamp is dead: tau >= mx-1 always => z = row-tau <= 1.
            // row in native-arith fp16 pairs (RTZ cast, one-time 32 insts)
            f16x2 rowh[32];
            #pragma unroll
            for (int jj = 0; jj < 32; ++jj) {
                h2f c; c.h = pk(row[2 * jj], row[2 * jj + 1]);
                rowh[jj] = c.f;
            }
            const f16x2 z16 = (f16x2)((_Float16)0.0f);
            const half2v one2 = pk(1.0f, 1.0f);

            // --- 6 bisection steps, packed fp16 (sign test only)
            #pragma unroll
            for (int it = 0; it < 6; ++it) {
                dm *= 0.5f;
                const float tau_m = tau_lo + dm;
                h2f ntu; ntu.h = pk(-tau_m, -tau_m);
                const f16x2 nt2 = ntu.f;
                f16x2 f0 = z16, f1 = z16, f2 = z16, f3 = z16;
                #pragma unroll
                for (int jj = 0; jj < 32; jj += 4) {
                    const f16x2 a0 = pmax16(rowh[jj + 0] + nt2, z16);
                    const f16x2 a1 = pmax16(rowh[jj + 1] + nt2, z16);
                    const f16x2 a2 = pmax16(rowh[jj + 2] + nt2, z16);
                    const f16x2 a3 = pmax16(rowh[jj + 3] + nt2, z16);
                    f0 = a0 * a0 + f0;     // v_pk_fma_f16 (contracted)
                    f1 = a1 * a1 + f1;
                    f2 = a2 * a2 + f2;
                    f3 = a3 * a3 + f3;
                }
                h2f r0, r1, r2, r3;
                r0.f = f0; r1.f = f1; r2.f = f2; r3.f = f3;
                float fs = dot2(r0.h, one2, -1.0f);
                fs = dot2(r1.h, one2, fs);
                fs = dot2(r2.h, one2, fs);
                fs = dot2(r3.h, one2, fs);
                tau_lo = (fs >= 0.0f) ? tau_m : tau_lo;
            }
            // --- Newton step 1, packed fp16 (coarse: 0.014 -> ~1e-3)
            float tau = tau_lo;
            {
                h2f ntu; ntu.h = pk(-tau, -tau);
                const f16x2 nt2 = ntu.f;
                f16x2 f0 = z16, f1 = z16;
                f16x2 s0 = z16, s1 = z16;
                #pragma unroll
                for (int jj = 0; jj < 32; jj += 2) {
                    const f16x2 a0 = pmax16(rowh[jj + 0] + nt2, z16);
                    const f16x2 a1 = pmax16(rowh[jj + 1] + nt2, z16);
                    f0 = a0 * a0 + f0;
                    f1 = a1 * a1 + f1;
                    s0 = s0 + a0;
                    s1 = s1 + a1;
                }
                h2f rf0, rf1, rs0, rs1;
                rf0.f = f0; rf1.f = f1; rs0.f = s0; rs1.f = s1;
                float f = dot2(rf0.h, one2, -1.0f);
                f = dot2(rf1.h, one2, f);
                float s = dot2(rs0.h, one2, 0.0f);
                s = dot2(rs1.h, one2, s);
                s += 1e-20f;
                // guarded: never moves left; overshoot is normalized away
                tau = tau + fmaxf(f, 0.0f) * __builtin_amdgcn_rcpf(s + s);
            }
            // --- Newton step 2, fp32 (restores tau to ~1e-5)
            {
                float f0 = -1.0f, f1 = 0.0f, f2 = 0.0f, f3 = 0.0f;
                float s0 = 0.0f, s1 = 0.0f, s2 = 0.0f, s3 = 0.0f;
                #pragma unroll
                for (int j = 0; j < 64; j += 4) {
                    const float a0 = fmaxf(row[j + 0] - tau, 0.0f);
                    const float a1 = fmaxf(row[j + 1] - tau, 0.0f);
                    const float a2 = fmaxf(row[j + 2] - tau, 0.0f);
                    const float a3 = fmaxf(row[j + 3] - tau, 0.0f);
                    f0 = fmaf(a0, a0, f0); f1 = fmaf(a1, a1, f1);
                    f2 = fmaf(a2, a2, f2); f3 = fmaf(a3, a3, f3);
                    s0 += a0; s1 += a1; s2 += a2; s3 += a3;
                }
                const float f = (f0 + f1) + (f2 + f3);
                const float s = ((s0 + s1) + (s2 + s3)) + 1e-20f;  // s >= 1/8
                tau = tau + fmaxf(f, 0.0f) * __builtin_amdgcn_rcpf(s + s);
            }
            // final p (unnormalized, fp32) + sum; normalization folded into av
            float s0 = 0.0f, s1 = 0.0f;
            #pragma unroll
            for (int j = 0; j < 64; j += 2) {
                float a0 = fmaxf(row[j + 0] - tau, 0.0f);
                float a1 = fmaxf(row[j + 1] - tau, 0.0f);
                a0 *= a0; a1 *= a1;
                row[j + 0] = a0; row[j + 1] = a1;
                s0 += a0; s1 += a1;
            }
            inv_sum = 1.0f / (s0 + s1);
        } else {
            // faithful general-alpha path (unused for this problem's alpha=1.5)
            const float inv = 1.0f / am1;
            float tau_m = tau_lo;
            float f_lo = -1.0f;
            #pragma unroll
            for (int j = 0; j < 64; ++j) f_lo += pgen(row[j] - tau_lo, inv);
            for (int it = 0; it < 30; ++it) {
                dm *= 0.5f;
                tau_m = tau_lo + dm;
                float f = -1.0f;
                #pragma unroll
                for (int j = 0; j < 64; ++j) f += pgen(row[j] - tau_m, inv);
                tau_lo = (f * f_lo >= 0.0f) ? tau_m : tau_lo;
            }
            float s = 0.0f;
            #pragma unroll
            for (int j = 0; j < 64; ++j) {
                const float pm = pgen(row[j] - tau_m, inv);
                row[j] = pm;
                s += pm;
            }
            inv_sum = 1.0f / s;
        }

        // av: res[h][lane] = inv_sum * sum_j p[j] * v[h][j]  via fp16 dot2
        #pragma unroll
        for (int ii = 0; ii < 32; ++ii) p2[ii] = pk(row[2 * ii], row[2 * ii + 1]);

        float acc[8];
        #pragma unroll
        for (int h = 0; h < 8; ++h) {
            float a0 = 0.0f, a1 = 0.0f;
            #pragma unroll
            for (int jc = 0; jc < 8; ++jc) {
                union { half8 h8; half2v h2[4]; } u;
                u.h8 = *(const half8*)&vT[t * TOKPAD + h * 32 + jc * 4];
                a0 = dot2(p2[jc * 4 + 0], u.h2[0], a0);
                a1 = dot2(p2[jc * 4 + 1], u.h2[1], a1);
                a0 = dot2(p2[jc * 4 + 2], u.h2[2], a0);
                a1 = dot2(p2[jc * 4 + 3], u.h2[3], a1);
            }
            acc[h] = a0 + a1;
        }
        // res -> LDS overlay of qT row t (wave-private row; same fp16 cast
        // as before => identical values feed the out MFMA)
        #pragma unroll
        for (int h = 0; h < 8; ++h)
            resL[t * 520 + h * 64 + lane] = (__fp16)(acc[h] * inv_sum);
    }
    __syncthreads();   // all 16 tokens' res in LDS -> out phase

    // ---- out phase: wave w computes out cols w*16..w*16+15 for 16 tokens.
    {
        floatx4 oacc = (floatx4){0.f, 0.f, 0.f, 0.f};
        const __fp16* rrow = resL + (size_t)m * 520 + quad * 8;   // token m
        const __fp16* wrow = wuh + (size_t)(w * 16 + m) * HHE + quad * 8;
        #pragma unroll
        for (int kc = 0; kc < 16; ++kc) {              // K=512 in 32-chunks
            const half8 bf = *(const half8*)(rrow + kc * 32);
            const half8 af = *(const half8*)(wrow + kc * 32);
            oacc = __builtin_amdgcn_mfma_f32_16x16x32_f16(af, bf, oacc, 0, 0, 0);
        }
        const int tok = tok0 + m;
        const int col = w * 16 + quad * 4;             // 4 consecutive out cols
        const float4 b4 = *(const float4*)&bu[col];
        float4 o;
        o.x = oacc[0] + b4.x;
        o.y = oacc[1] + b4.y;
        o.z = oacc[2] + b4.z;
        o.w = oacc[3] + b4.w;
        *(float4*)&out[(size_t)tok * 64 + col] = o;
    }
}

// ---------------------------------------------------------------------------
extern "C" void kernel_launch(void* const* d_in, const int* in_sizes, int n_in,
                              void* d_out, int out_size, void* d_ws, size_t ws_size,
                              hipStream_t stream)
{
    const float* x     = (const float*)d_in[0];
    const float* alpha = (const float*)d_in[1];
    const float* Wk    = (const float*)d_in[2];
    const float* bk    = (const float*)d_in[3];
    const float* Wq    = (const float*)d_in[4];
    const float* bq    = (const float*)d_in[5];
    const float* Wv    = (const float*)d_in[6];
    const float* bv    = (const float*)d_in[7];
    const float* Wu    = (const float*)d_in[8];
    const float* bu    = (const float*)d_in[9];
    float* out = (float*)d_out;

    // workspace (fp16 units): wkh/wqh/wvh/wuh 32768 each
    __fp16* wkh  = (__fp16*)d_ws;
    __fp16* wqh  = wkh + (size_t)HHE * EDIM;
    __fp16* wvh  = wqh + (size_t)HHE * EDIM;
    __fp16* wuh  = wvh + (size_t)HHE * EDIM;

    cvt_fp16_kernel<<<dim3(16, 4), 256, 0, stream>>>(
        Wk, Wq, Wv, Wu, wkh, wqh, wvh, wuh, alpha);
    qkv_attn_out_kernel<<<NTOK / TPB, 256, 0, stream>>>(
        x, wkh, bk, wqh, bq, wvh, bv, wuh, bu, out, alpha);
}

// Round 7
// 157.125 us; speedup vs baseline: 1.1627x; 1.0031x over previous
//
#include <hip/hip_runtime.h>
#include <math.h>

// Problem constants (b=8, c=2048, e=64, h=8)
#define NTOK 16384
#define EDIM 64
#define HHE  512   // h*e
#define TPB  16    // tokens per block (TPB=8 falsified in R20)
#define TOKPAD 260 // half2 slots per token row: 256 + 4 pad (16B-aligned rows)

typedef _Float16 half8 __attribute__((ext_vector_type(8)));   // MFMA operand type
typedef __fp16   half2v __attribute__((ext_vector_type(2)));  // builtin V2h type
typedef _Float16 f16x2 __attribute__((ext_vector_type(2)));
typedef float    floatx4 __attribute__((ext_vector_type(4)));

__device__ __forceinline__ half8 cvt8(const float4 a, const float4 b) {
    half8 h;
    h[0] = (_Float16)a.x; h[1] = (_Float16)a.y;
    h[2] = (_Float16)a.z; h[3] = (_Float16)a.w;
    h[4] = (_Float16)b.x; h[5] = (_Float16)b.y;
    h[6] = (_Float16)b.z; h[7] = (_Float16)b.w;
    return h;
}

// fp32 += half2 . half2 (v_dot2_f32_f16)
__device__ __forceinline__ float dot2(half2v a, half2v b, float c) {
#if __has_builtin(__builtin_amdgcn_fdot2)
    return __builtin_amdgcn_fdot2(a, b, c, false);
#else
    return fmaf((float)a[0], (float)b[0], fmaf((float)a[1], (float)b[1], c));
#endif
}
__device__ __forceinline__ half2v pk(float x, float y) {
    return __builtin_amdgcn_cvt_pkrtz(x, y);   // v_cvt_pkrtz_f16_f32 (V2h)
}
union h2u { half2v h; f16x2 f; unsigned int u; };

// ---- FORCED packed-fp16 VOP3P ops on 32-bit pair registers (inline asm;
// hipcc does not form these from vector types — proven via counters in
// R21/R22: VALU busy-time and VGPR identical to scalar fp32 baseline).
// 16-bit SIMD path is genuinely 2-wide per lane (unlike pk_f32 = half-rate).
__device__ __forceinline__ unsigned pka16(unsigned a, unsigned b) {
    unsigned d;
    asm("v_pk_add_f16 %0, %1, %2" : "=v"(d) : "v"(a), "v"(b));
    return d;
}
__device__ __forceinline__ unsigned pkmax16(unsigned a, unsigned b) {
    unsigned d;
    asm("v_pk_max_f16 %0, %1, %2" : "=v"(d) : "v"(a), "v"(b));
    return d;
}
__device__ __forceinline__ unsigned pkmul16(unsigned a, unsigned b) {
    unsigned d;
    asm("v_pk_mul_f16 %0, %1, %2" : "=v"(d) : "v"(a), "v"(b));
    return d;
}
// clamp pair to [0,inf): max(x, +0.0 pair) ; 0u is the +0|+0 fp16 pair
__device__ __forceinline__ unsigned pkrelu16(unsigned x, unsigned z0) {
    return pkmax16(x, z0);
}
__device__ __forceinline__ float dot2u(unsigned a, unsigned b, float c) {
    h2u ua, ub; ua.u = a; ub.u = b;
    return dot2(ua.h, ub.h, c);
}

__device__ __forceinline__ float pgen(float z, float inv) {
    return z > 0.0f ? exp2f(inv * log2f(fmaxf(z, 1e-30f))) : 0.0f;
}

// ---------------------------------------------------------------------------
// Kernel 0: fp32 -> fp16 (RTN cast) for the 4 weight matrices only.
// Wq pre-scaled by (alpha-1)/sqrt(e) so the score scale vanishes downstream.
// ---------------------------------------------------------------------------
__global__ __launch_bounds__(256) void cvt_fp16_kernel(
    const float* __restrict__ Wk, const float* __restrict__ Wq,
    const float* __restrict__ Wv, const float* __restrict__ Wu,
    __fp16* __restrict__ wkh, __fp16* __restrict__ wqh,
    __fp16* __restrict__ wvh, __fp16* __restrict__ wuh,
    const float* alpha_p)
{
    const int z = blockIdx.y;
    const float* src; __fp16* dst;
    float s = 1.0f;
    if      (z == 0) { src = Wk; dst = wkh; }
    else if (z == 1) { src = Wq; dst = wqh; s = (alpha_p[0] - 1.0f) * 0.125f; }
    else if (z == 2) { src = Wv; dst = wvh; }
    else             { src = Wu; dst = wuh; }
    const int idx = (blockIdx.x * 256 + threadIdx.x) * 8;
    float4 a = *(const float4*)(src + idx);
    float4 b = *(const float4*)(src + idx + 4);
    a.x *= s; a.y *= s; a.z *= s; a.w *= s;
    b.x *= s; b.y *= s; b.z *= s; b.w *= s;
    *(half8*)(dst + idx) = cvt8(a, b);
}

// ---------------------------------------------------------------------------
// Kernel 1: FULLY FUSED qkv + entmax-attention + output projection.
// R23: the entire alpha=1.5 root-find runs on fp16 PAIRS held as uint32
// (rowh[32]); clamps are forced v_pk_add_f16/v_pk_max_f16 (inline asm),
// and all f/s accumulations are single full-rate v_dot2_f32_f16
// (f += a0^2+a1^2 and s += a0+a1 are ONE instruction per pair).
// The fp32 row[64] array is GONE in the fast path -> register pressure
// (and the suspected AGPR shuffling behind VGPR_Count=80) collapses.
// Accuracy: tau error from fp16 row rounding ~1e-3; p goes through an
// fp16 cast anyway -> same accuracy class (absmax budget 1/64).
// ---------------------------------------------------------------------------
__global__ __launch_bounds__(256) void qkv_attn_out_kernel(
    const float* __restrict__ x,
    const __fp16* __restrict__ wkh, const float* __restrict__ bk,
    const __fp16* __restrict__ wqh, const float* __restrict__ bq,
    const __fp16* __restrict__ wvh, const float* __restrict__ bv,
    const __fp16* __restrict__ wuh, const float* __restrict__ bu,
    float* __restrict__ out, const float* alpha_p)
{
    __shared__ __align__(16) half2v qT[TPB * TOKPAD];  // [tok][i*4+hpair] -> res overlay
    __shared__ __align__(16) half2v kT[TPB * TOKPAD];  // [tok][j*4 + hpair]
    __shared__ __align__(16) half2v vT[TPB * TOKPAD];  // [tok][h*32 + jpair]

    const int tid  = threadIdx.x;
    const int lane = tid & 63;
    const int w    = tid >> 6;
    const int tok0 = blockIdx.x * TPB;

    const int m    = lane & 15;            // token (B row)
    const int quad = lane >> 4;

    const float alpha = alpha_p[0];
    const float am1   = alpha - 1.0f;
    const float s_q   = am1 * 0.125f;      // matches cvt kernel's Wq scale

    // ---- x B-fragments: fp32 load + RTN cast (identical to old cvt path)
    const float* xrow = x + (size_t)(tok0 + m) * EDIM + quad * 8;
    half8 bfr[2];
    {
        const float4 a0 = *(const float4*)(xrow);
        const float4 a1 = *(const float4*)(xrow + 4);
        const float4 a2 = *(const float4*)(xrow + 32);
        const float4 a3 = *(const float4*)(xrow + 36);
        bfr[0] = cvt8(a0, a1);
        bfr[1] = cvt8(a2, a3);
    }

    // ---- producer: units w*3 .. w*3+2; unit = z*4 + ntile
    #pragma unroll
    for (int uu = 0; uu < 3; ++uu) {
        const int unit = w * 3 + uu;
        const int z    = unit >> 2;            // 0=k, 1=q, 2=v
        const int col0 = (unit & 3) * 128;
        const __fp16* W   = (z == 0) ? wkh : (z == 1) ? wqh : wvh;
        const float* bias = (z == 0) ? bk : (z == 1) ? bq : bv;
        half2v* dstT      = (z == 0) ? kT : (z == 1) ? qT : vT;
        // q path: W pre-scaled; bias scaled here via exact fmaf (bs=1 for k)
        const float bs    = (z == 1) ? s_q : 1.0f;

        #pragma unroll
        for (int ct = 0; ct < 8; ++ct) {
            const int n = col0 + ct * 16 + m;
            // permuted W row for q/k; natural for v
            const int grow = (z < 2) ? ((n & 7) * 64 + (n >> 3)) : n;
            const __fp16* wrow = W + (size_t)grow * EDIM + quad * 8;
            floatx4 acc = (floatx4){0.f, 0.f, 0.f, 0.f};
            #pragma unroll
            for (int kc = 0; kc < 2; ++kc) {
                const half8 af = *(const half8*)(wrow + kc * 32);  // direct fp16
                acc = __builtin_amdgcn_mfma_f32_16x16x32_f16(af, bfr[kc], acc, 0, 0, 0);
            }
            // lane's 4 regs = D rows quad*4+0..3, D col = m (token)
            h2u p0, p1;
            if (z < 2) {
                // output rows g(n'): h = 4*(quad&1)+reg, j = col0/8+ct*2+(quad>>1)
                const int hbase = 4 * (quad & 1);
                const int j     = (col0 >> 3) + ct * 2 + (quad >> 1);
                float o0 = fmaf(bias[(hbase + 0) * 64 + j], bs, acc[0]);
                float o1 = fmaf(bias[(hbase + 1) * 64 + j], bs, acc[1]);
                float o2 = fmaf(bias[(hbase + 2) * 64 + j], bs, acc[2]);
                float o3 = fmaf(bias[(hbase + 3) * 64 + j], bs, acc[3]);
                p0.h = pk(o0, o1);                 // h-pair 2*(quad&1)
                p1.h = pk(o2, o3);                 // h-pair 2*(quad&1)+1
                uint2 st; st.x = p0.u; st.y = p1.u;
                *(uint2*)&dstT[m * TOKPAD + j * 4 + 2 * (quad & 1)] = st;
            } else {
                // natural: cols nn..nn+3 = v[h][jj..jj+3]
                const int nn = col0 + ct * 16 + quad * 4;
                const int h  = nn >> 6;
                const int jj = nn & 63;
                const float4 b4 = *(const float4*)&bias[nn];
                p0.h = pk(acc[0] + b4.x, acc[1] + b4.y);
                p1.h = pk(acc[2] + b4.z, acc[3] + b4.w);
                uint2 st; st.x = p0.u; st.y = p1.u;
                *(uint2*)&dstT[m * TOKPAD + h * 32 + (jj >> 1)] = st;
            }
        }
    }
    __syncthreads();   // producer (all waves write all 16 tokens) -> consumer

    __fp16* resL = (__fp16*)qT;            // res overlay: row stride 520 halves

    // ---- consumer: each wave runs 4 tokens serially
    for (int i = 0; i < 4; ++i) {
        const int t = w * 4 + i;

        union { half8 h8; half2v h2[4]; } uq;
        uq.h8 = *(const half8*)&qT[t * TOKPAD + lane * 4];  // qT row t dead after this

        float inv_sum;
        half2v p2[32];

        if (am1 == 0.5f) {
            // ---- QK dot row -> fp16 pairs directly (fp32 accum in dot2,
            // then one cvt_pkrtz per pair). No fp32 row array.
            unsigned rowh[32];
            #pragma unroll
            for (int j = 0; j < 64; j += 2) {
                union { half8 h8; half2v h2[4]; } u0, u1;
                u0.h8 = *(const half8*)&kT[t * TOKPAD + j * 4];        // broadcast b128
                u1.h8 = *(const half8*)&kT[t * TOKPAD + (j + 1) * 4];
                float d0 = dot2(uq.h2[0], u0.h2[0], 0.0f);
                float d1 = dot2(uq.h2[0], u1.h2[0], 0.0f);
                d0 = dot2(uq.h2[1], u0.h2[1], d0);
                d1 = dot2(uq.h2[1], u1.h2[1], d1);
                d0 = dot2(uq.h2[2], u0.h2[2], d0);
                d1 = dot2(uq.h2[2], u1.h2[2], d1);
                d0 = dot2(uq.h2[3], u0.h2[3], d0);
                d1 = dot2(uq.h2[3], u1.h2[3], d1);
                h2u c; c.h = pk(d0, d1);
                rowh[j >> 1] = c.u;
            }

            // ---- max via pk_max tree (exact fp16 max)
            unsigned t16[16];
            #pragma unroll
            for (int jj = 0; jj < 16; ++jj) t16[jj] = pkmax16(rowh[2*jj], rowh[2*jj+1]);
            #pragma unroll
            for (int jj = 0; jj < 8; ++jj)  t16[jj] = pkmax16(t16[jj], t16[jj+8]);
            #pragma unroll
            for (int jj = 0; jj < 4; ++jj)  t16[jj] = pkmax16(t16[jj], t16[jj+4]);
            t16[0] = pkmax16(pkmax16(t16[0], t16[1]), pkmax16(t16[2], t16[3]));
            h2u mu; mu.u = t16[0];
            const float mx = fmaxf((float)mu.f[0], (float)mu.f[1]);

            float tau_lo = mx - 1.0f;                     // f(tau_lo) >= 0 provably
            float dm = tau_lo - (mx - exp2f(-6.0f * am1)); // = -(tau_hi-tau_lo)
            dm = -dm;
            const unsigned z0 = 0u;                       // +0|+0 fp16 pair
            const half2v one2 = pk(1.0f, 1.0f);

            // ---- 6 bisection steps, forced packed fp16 + dot2 f-sums
            #pragma unroll
            for (int it = 0; it < 6; ++it) {
                dm *= 0.5f;
                const float tau_m = tau_lo + dm;
                h2u ntc; ntc.h = pk(-tau_m, -tau_m);
                const unsigned nt = ntc.u;
                float f0 = -1.0f, f1 = 0.0f, f2 = 0.0f, f3 = 0.0f;
                #pragma unroll
                for (int jj = 0; jj < 32; jj += 4) {
                    const unsigned a0 = pkrelu16(pka16(rowh[jj + 0], nt), z0);
                    const unsigned a1 = pkrelu16(pka16(rowh[jj + 1], nt), z0);
                    const unsigned a2 = pkrelu16(pka16(rowh[jj + 2], nt), z0);
                    const unsigned a3 = pkrelu16(pka16(rowh[jj + 3], nt), z0);
                    f0 = dot2u(a0, a0, f0);   // += a0lo^2 + a0hi^2 (one inst)
                    f1 = dot2u(a1, a1, f1);
                    f2 = dot2u(a2, a2, f2);
                    f3 = dot2u(a3, a3, f3);
                }
                const float f = (f0 + f1) + (f2 + f3);
                tau_lo = (f >= 0.0f) ? tau_m : tau_lo;
            }
            // ---- 2 guarded Newton steps, packed fp16 (f and s via dot2)
            float tau = tau_lo;
            #pragma unroll
            for (int it = 0; it < 2; ++it) {
                h2u ntc; ntc.h = pk(-tau, -tau);
                const unsigned nt = ntc.u;
                float f0 = -1.0f, f1 = 0.0f;
                float s0 = 0.0f, s1 = 0.0f;
                #pragma unroll
                for (int jj = 0; jj < 32; jj += 2) {
                    const unsigned a0 = pkrelu16(pka16(rowh[jj + 0], nt), z0);
                    const unsigned a1 = pkrelu16(pka16(rowh[jj + 1], nt), z0);
                    f0 = dot2u(a0, a0, f0);
                    f1 = dot2u(a1, a1, f1);
                    h2u ua0, ua1; ua0.u = a0; ua1.u = a1;
                    s0 = dot2(ua0.h, one2, s0);
                    s1 = dot2(ua1.h, one2, s1);
                }
                const float f = f0 + f1;
                const float s = (s0 + s1) + 1e-20f;       // s >= ~1 at root region
                tau = tau + fmaxf(f, 0.0f) * __builtin_amdgcn_rcpf(s + s);
            }
            // ---- final p: p2 = a*a in fp16 (pk_mul), sum via dot2
            {
                h2u ntc; ntc.h = pk(-tau, -tau);
                const unsigned nt = ntc.u;
                float s0 = 0.0f, s1 = 0.0f;
                #pragma unroll
                for (int jj = 0; jj < 32; jj += 2) {
                    const unsigned a0 = pkrelu16(pka16(rowh[jj + 0], nt), z0);
                    const unsigned a1 = pkrelu16(pka16(rowh[jj + 1], nt), z0);
                    s0 = dot2u(a0, a0, s0);
                    s1 = dot2u(a1, a1, s1);
                    h2u q0, q1;
                    q0.u = pkmul16(a0, a0);
                    q1.u = pkmul16(a1, a1);
                    p2[jj + 0] = q0.h;
                    p2[jj + 1] = q1.h;
                }
                inv_sum = __builtin_amdgcn_rcpf(s0 + s1);  // ~1ulp; under fp16 cast
            }
        } else {
            // faithful general-alpha path (unused for this problem's alpha=1.5):
            // fp32 dot row recomputed here so the fast path carries no fp32 row.
            float row[64];
            #pragma unroll
            for (int j = 0; j < 64; j += 2) {
                union { half8 h8; half2v h2[4]; } u0, u1;
                u0.h8 = *(const half8*)&kT[t * TOKPAD + j * 4];
                u1.h8 = *(const half8*)&kT[t * TOKPAD + (j + 1) * 4];
                float d0 = dot2(uq.h2[0], u0.h2[0], 0.0f);
                float d1 = dot2(uq.h2[0], u1.h2[0], 0.0f);
                d0 = dot2(uq.h2[1], u0.h2[1], d0);
                d1 = dot2(uq.h2[1], u1.h2[1], d1);
                d0 = dot2(uq.h2[2], u0.h2[2], d0);
                d1 = dot2(uq.h2[2], u1.h2[2], d1);
                d0 = dot2(uq.h2[3], u0.h2[3], d0);
                d1 = dot2(uq.h2[3], u1.h2[3], d1);
                row[j] = d0; row[j + 1] = d1;
            }
            float mx = row[0];
            #pragma unroll
            for (int j = 1; j < 64; ++j) mx = fmaxf(mx, row[j]);

            float tau_lo = mx - 1.0f;
            const float tau_hi = mx - exp2f(-6.0f * am1);
            float dm = tau_hi - tau_lo;
            const float inv = 1.0f / am1;
            float tau_m = tau_lo;
            float f_lo = -1.0f;
            #pragma unroll
            for (int j = 0; j < 64; ++j) f_lo += pgen(row[j] - tau_lo, inv);
            for (int it = 0; it < 30; ++it) {
                dm *= 0.5f;
                tau_m = tau_lo + dm;
                float f = -1.0f;
                #pragma unroll
                for (int j = 0; j < 64; ++j) f += pgen(row[j] - tau_m, inv);
                tau_lo = (f * f_lo >= 0.0f) ? tau_m : tau_lo;
            }
            float s = 0.0f;
            #pragma unroll
            for (int j = 0; j < 64; ++j) {
                const float pm = pgen(row[j] - tau_m, inv);
                row[j] = pm;
                s += pm;
            }
            inv_sum = 1.0f / s;
            #pragma unroll
            for (int ii = 0; ii < 32; ++ii) p2[ii] = pk(row[2 * ii], row[2 * ii + 1]);
        }

        // av: res[h][lane] = inv_sum * sum_j p[j] * v[h][j]  via fp16 dot2
        float acc[8];
        #pragma unroll
        for (int h = 0; h < 8; ++h) {
            float a0 = 0.0f, a1 = 0.0f;
            #pragma unroll
            for (int jc = 0; jc < 8; ++jc) {
                union { half8 h8; half2v h2[4]; } u;
                u.h8 = *(const half8*)&vT[t * TOKPAD + h * 32 + jc * 4];
                a0 = dot2(p2[jc * 4 + 0], u.h2[0], a0);
                a1 = dot2(p2[jc * 4 + 1], u.h2[1], a1);
                a0 = dot2(p2[jc * 4 + 2], u.h2[2], a0);
                a1 = dot2(p2[jc * 4 + 3], u.h2[3], a1);
            }
            acc[h] = a0 + a1;
        }
        // res -> LDS overlay of qT row t (wave-private row)
        #pragma unroll
        for (int h = 0; h < 8; ++h)
            resL[t * 520 + h * 64 + lane] = (__fp16)(acc[h] * inv_sum);
    }
    __syncthreads();   // all 16 tokens' res in LDS -> out phase

    // ---- out phase: wave w computes out cols w*16..w*16+15 for 16 tokens.
    {
        floatx4 oacc = (floatx4){0.f, 0.f, 0.f, 0.f};
        const __fp16* rrow = resL + (size_t)m * 520 + quad * 8;   // token m
        const __fp16* wrow = wuh + (size_t)(w * 16 + m) * HHE + quad * 8;
        #pragma unroll
        for (int kc = 0; kc < 16; ++kc) {              // K=512 in 32-chunks
            const half8 bf = *(const half8*)(rrow + kc * 32);
            const half8 af = *(const half8*)(wrow + kc * 32);
            oacc = __builtin_amdgcn_mfma_f32_16x16x32_f16(af, bf, oacc, 0, 0, 0);
        }
        const int tok = tok0 + m;
        const int col = w * 16 + quad * 4;             // 4 consecutive out cols
        const float4 b4 = *(const float4*)&bu[col];
        float4 o;
        o.x = oacc[0] + b4.x;
        o.y = oacc[1] + b4.y;
        o.z = oacc[2] + b4.z;
        o.w = oacc[3] + b4.w;
        *(float4*)&out[(size_t)tok * 64 + col] = o;
    }
}

// ---------------------------------------------------------------------------
extern "C" void kernel_launch(void* const* d_in, const int* in_sizes, int n_in,
                              void* d_out, int out_size, void* d_ws, size_t ws_size,
                              hipStream_t stream)
{
    const float* x     = (const float*)d_in[0];
    const float* alpha = (const float*)d_in[1];
    const float* Wk    = (const float*)d_in[2];
    const float* bk    = (const float*)d_in[3];
    const float* Wq    = (const float*)d_in[4];
    const float* bq    = (const float*)d_in[5];
    const float* Wv    = (const float*)d_in[6];
    const float* bv    = (const float*)d_in[7];
    const float* Wu    = (const float*)d_in[8];
    const float* bu    = (const float*)d_in[9];
    float* out = (float*)d_out;

    // workspace (fp16 units): wkh/wqh/wvh/wuh 32768 each
    __fp16* wkh  = (__fp16*)d_ws;
    __fp16* wqh  = wkh + (size_t)HHE * EDIM;
    __fp16* wvh  = wqh + (size_t)HHE * EDIM;
    __fp16* wuh  = wvh + (size_t)HHE * EDIM;

    cvt_fp16_kernel<<<dim3(16, 4), 256, 0, stream>>>(
        Wk, Wq, Wv, Wu, wkh, wqh, wvh, wuh, alpha);
    qkv_attn_out_kernel<<<NTOK / TPB, 256, 0, stream>>>(
        x, wkh, bk, wqh, bq, wvh, bv, wuh, bu, out, alpha);
}